// Round 1
// baseline (274.461 us; speedup 1.0000x reference)
//
#include <hip/hip_runtime.h>
#include <stdint.h>

#define B_ 2048
#define T_ 256
#define V_ 128
#define E_ 128
#define H_ 64
#define G4_ 256  // 4*H
#define POS_W 20.0f

typedef _Float16 half1;
typedef _Float16 half2_t __attribute__((ext_vector_type(2)));

#if __has_builtin(__builtin_amdgcn_fdot2)
#define FDOT2(a, b, c) __builtin_amdgcn_fdot2((a), (b), (c), false)
#else
#define FDOT2(a, b, c) ((c) + (float)(a)[0] * (float)(b)[0] + (float)(a)[1] * (float)(b)[1])
#endif

#if __has_builtin(__builtin_amdgcn_exp2f)
#define EXP2F(x) __builtin_amdgcn_exp2f(x)
#else
#define EXP2F(x) exp2f(x)
#endif

#if __has_builtin(__builtin_amdgcn_rcpf)
#define RCPF(x) __builtin_amdgcn_rcpf(x)
#else
#define RCPF(x) (1.0f / (x))
#endif

__device__ __forceinline__ half2_t bchalf2(uint32_t u) {
    return __builtin_bit_cast(half2_t, u);
}

__device__ __forceinline__ float sigm(float x) {
    // 1/(1+2^(-x*log2e)); saturates correctly at +-inf (rcp(inf)=0)
    return RCPF(1.0f + EXP2F(-1.44269504f * x));
}

__device__ __forceinline__ float tanhr(float x) {
    // clamp so exp2 can't produce inf -> NaN; tanh(16) == 1 to fp32
    float xx = fminf(fmaxf(x, -16.0f), 16.0f);
    float t = EXP2F(2.88539008f * xx);  // e^(2x)
    return (t - 1.0f) * RCPF(t + 1.0f);
}

// ---------------------------------------------------------------------------
// Kernel 1: proj[v][l*4+g] = dot(emb[v], W_ih[g*64+l]) + b_ih[g*64+l] + b_hh[g*64+l]
// stored as f16, permuted so lane L of the LSTM kernel loads 4 contiguous halves.
// ---------------------------------------------------------------------------
__global__ void k_proj(const float* __restrict__ emb, const float* __restrict__ Wih,
                       const float* __restrict__ bih, const float* __restrict__ bhh,
                       half1* __restrict__ proj) {
    int v = blockIdx.x;        // 0..127
    int tid = threadIdx.x;     // 0..255, tid = l*4+g
    int l = tid >> 2, g = tid & 3;
    int row = g * 64 + l;
    const float4* e4 = (const float4*)(emb + v * E_);
    const float4* w4 = (const float4*)(Wih + row * E_);
    float acc = bih[row] + bhh[row];
#pragma unroll
    for (int i = 0; i < E_ / 4; ++i) {
        float4 a = e4[i];
        float4 b = w4[i];
        acc += a.x * b.x + a.y * b.y + a.z * b.z + a.w * b.w;
    }
    proj[v * G4_ + tid] = (half1)acc;  // coalesced: addr = v*256 + tid
}

// ---------------------------------------------------------------------------
// Kernel 2: repack W_hh [256,64] f32 -> whh_perm as half2:
// flat n = l*128 + g*32 + j  <-  (W_hh[g*64+l][2j], W_hh[g*64+l][2j+1])
// so lane L's 128 half2 weights are one contiguous 512B chunk.
// ---------------------------------------------------------------------------
__global__ void k_whh(const float* __restrict__ Whh, uint32_t* __restrict__ whh) {
    int n = blockIdx.x * 256 + threadIdx.x;  // 0..8191
    int j = n & 31;
    int g = (n >> 5) & 3;
    int l = n >> 7;
    int row = g * 64 + l;
    half2_t h2 = {(half1)Whh[row * H_ + 2 * j], (half1)Whh[row * H_ + 2 * j + 1]};
    whh[n] = __builtin_bit_cast(uint32_t, h2);
}

// ---------------------------------------------------------------------------
// Kernel 3: the recurrence. One wave (64 threads) per batch element.
// Lane L owns hidden unit L: carries c[L] in a register, computes all 4 gates
// for unit L via v_dot2_f32_f16 against f16 W_hh held entirely in VGPRs.
// h is exchanged through a 128B LDS buffer (wave-lockstep, no barrier needed).
// ---------------------------------------------------------------------------
__launch_bounds__(64, 2)
__global__ void k_lstm(const int* __restrict__ x, const uint32_t* __restrict__ whh,
                       const half1* __restrict__ proj, const float* __restrict__ Wfc,
                       const float* __restrict__ bfc, float* __restrict__ logits) {
    int b = blockIdx.x;
    int L = threadIdx.x;  // 0..63

    __shared__ __align__(16) uint32_t hbuf[32];  // 64 halves: h[0..63]
    __shared__ int xrow[T_];

    // stage this batch element's index row into LDS
#pragma unroll
    for (int i = 0; i < T_ / 64; ++i) xrow[i * 64 + L] = x[b * T_ + i * 64 + L];
    if (L < 32) hbuf[L] = 0u;  // h0 = 0
    __syncthreads();

    // load lane L's W_hh slice: 128 half2 = 128 VGPRs, fully unrolled constant idx
    half2_t w[4][32];
    {
        const uint4* wb4 = (const uint4*)(whh + L * 128);
#pragma unroll
        for (int i = 0; i < 32; ++i) {
            uint4 q = wb4[i];
            int n = i * 4;
            w[(n + 0) >> 5][(n + 0) & 31] = bchalf2(q.x);
            w[(n + 1) >> 5][(n + 1) & 31] = bchalf2(q.y);
            w[(n + 2) >> 5][(n + 2) & 31] = bchalf2(q.z);
            w[(n + 3) >> 5][(n + 3) & 31] = bchalf2(q.w);
        }
    }

    float c = 0.0f;
    float h = 0.0f;

    // software-pipelined input projection (one step ahead)
    int v0 = xrow[0];
    uint2 pu = *(const uint2*)(proj + v0 * G4_ + L * 4);

    const uint4* hb4 = (const uint4*)hbuf;
    half1* hb16 = (half1*)&hbuf[0];

    for (int t = 0; t < T_; ++t) {
        // prefetch next step's projection (dummy row 0 on last iter; harmless)
        int vn = xrow[(t + 1) & (T_ - 1)];
        uint2 pn = *(const uint2*)(proj + vn * G4_ + L * 4);

        float ai = 0.f, af = 0.f, ag = 0.f, ao = 0.f;
#pragma unroll
        for (int q = 0; q < 8; ++q) {
            uint4 hh = hb4[q];  // broadcast ds_read_b128 (uniform address)
            half2_t hv0 = bchalf2(hh.x), hv1 = bchalf2(hh.y);
            half2_t hv2 = bchalf2(hh.z), hv3 = bchalf2(hh.w);
            ai = FDOT2(w[0][q * 4 + 0], hv0, ai);
            af = FDOT2(w[1][q * 4 + 0], hv0, af);
            ag = FDOT2(w[2][q * 4 + 0], hv0, ag);
            ao = FDOT2(w[3][q * 4 + 0], hv0, ao);
            ai = FDOT2(w[0][q * 4 + 1], hv1, ai);
            af = FDOT2(w[1][q * 4 + 1], hv1, af);
            ag = FDOT2(w[2][q * 4 + 1], hv1, ag);
            ao = FDOT2(w[3][q * 4 + 1], hv1, ao);
            ai = FDOT2(w[0][q * 4 + 2], hv2, ai);
            af = FDOT2(w[1][q * 4 + 2], hv2, af);
            ag = FDOT2(w[2][q * 4 + 2], hv2, ag);
            ao = FDOT2(w[3][q * 4 + 2], hv2, ao);
            ai = FDOT2(w[0][q * 4 + 3], hv3, ai);
            af = FDOT2(w[1][q * 4 + 3], hv3, af);
            ag = FDOT2(w[2][q * 4 + 3], hv3, ag);
            ao = FDOT2(w[3][q * 4 + 3], hv3, ao);
        }

        half2_t pa = bchalf2(pu.x), pb = bchalf2(pu.y);
        float gi = ai + (float)pa[0];
        float gf = af + (float)pa[1];
        float gg = ag + (float)pb[0];
        float go = ao + (float)pb[1];

        float i_ = sigm(gi);
        float f_ = sigm(gf);
        float g_ = tanhr(gg);
        float o_ = sigm(go);
        c = f_ * c + i_ * g_;
        h = o_ * tanhr(c);

        // publish h[L] for next step; single wave => lockstep, no barrier
        __builtin_amdgcn_wave_barrier();
        hb16[L] = (half1)h;
        __builtin_amdgcn_wave_barrier();

        pu = pn;
    }

    // logits[b] = sum_L h[L] * W_fc[L] + b_fc
    float contrib = h * Wfc[L];
#pragma unroll
    for (int off = 32; off > 0; off >>= 1) contrib += __shfl_down(contrib, off, 64);
    if (L == 0) logits[b] = contrib + bfc[0];
}

// ---------------------------------------------------------------------------
// Kernel 4: BCEWithLogits(pos_weight) mean over B. Single block, deterministic.
// ---------------------------------------------------------------------------
__global__ void k_loss(const float* __restrict__ logits, const float* __restrict__ targets,
                       float* __restrict__ loss_out) {
    __shared__ float red[256];
    int tid = threadIdx.x;
    float acc = 0.0f;
    for (int i = tid; i < B_; i += 256) {
        float z = logits[i];
        float tg = targets[i];
        // log sigmoid(z) = min(z,0) - log1p(exp(-|z|)); log sigmoid(-z) = that - z
        float e = EXP2F(-1.44269504f * fabsf(z));
        float lsp = fminf(z, 0.0f) - log1pf(e);
        float lsn = lsp - z;
        acc += -(POS_W * tg * lsp + (1.0f - tg) * lsn);
    }
    red[tid] = acc;
    __syncthreads();
#pragma unroll
    for (int s = 128; s > 0; s >>= 1) {
        if (tid < s) red[tid] += red[tid + s];
        __syncthreads();
    }
    if (tid == 0) loss_out[0] = red[0] * (1.0f / (float)B_);
}

// ---------------------------------------------------------------------------
extern "C" void kernel_launch(void* const* d_in, const int* in_sizes, int n_in,
                              void* d_out, int out_size, void* d_ws, size_t ws_size,
                              hipStream_t stream) {
    const int* x = (const int*)d_in[0];
    const float* targets = (const float*)d_in[1];
    const float* emb = (const float*)d_in[2];
    const float* Wih = (const float*)d_in[3];
    const float* Whh = (const float*)d_in[4];
    const float* bih = (const float*)d_in[5];
    const float* bhh = (const float*)d_in[6];
    const float* Wfc = (const float*)d_in[7];
    const float* bfc = (const float*)d_in[8];
    float* out = (float*)d_out;  // [0..2047] logits, [2048] loss

    half1* proj = (half1*)d_ws;                              // 128*256*2 = 64 KiB
    uint32_t* whh = (uint32_t*)((char*)d_ws + 64 * 1024);    // 8192*4   = 32 KiB

    k_proj<<<dim3(V_), dim3(256), 0, stream>>>(emb, Wih, bih, bhh, proj);
    k_whh<<<dim3(32), dim3(256), 0, stream>>>(Whh, whh);
    k_lstm<<<dim3(B_), dim3(64), 0, stream>>>(x, whh, proj, Wfc, bfc, out);
    k_loss<<<dim3(1), dim3(256), 0, stream>>>(out, targets, out + B_);
}

// Round 2
// 273.313 us; speedup vs baseline: 1.0042x; 1.0042x over previous
//
#include <hip/hip_runtime.h>
#include <stdint.h>

#define B_ 2048
#define T_ 256
#define V_ 128
#define E_ 128
#define H_ 64
#define G4_ 256  // 4*H
#define POS_W 20.0f

typedef _Float16 half1;
typedef _Float16 half2_t __attribute__((ext_vector_type(2)));

#if __has_builtin(__builtin_amdgcn_fdot2)
#define FDOT2(a, b, c) __builtin_amdgcn_fdot2((a), (b), (c), false)
#else
#define FDOT2(a, b, c) ((c) + (float)(a)[0] * (float)(b)[0] + (float)(a)[1] * (float)(b)[1])
#endif

#if __has_builtin(__builtin_amdgcn_exp2f)
#define EXP2F(x) __builtin_amdgcn_exp2f(x)
#else
#define EXP2F(x) exp2f(x)
#endif

#if __has_builtin(__builtin_amdgcn_rcpf)
#define RCPF(x) __builtin_amdgcn_rcpf(x)
#else
#define RCPF(x) (1.0f / (x))
#endif

__device__ __forceinline__ half2_t bchalf2(uint32_t u) {
    return __builtin_bit_cast(half2_t, u);
}

__device__ __forceinline__ float sigm(float x) {
    // 1/(1+2^(-x*log2e)); saturates correctly at +-inf (rcp(inf)=0)
    return RCPF(1.0f + EXP2F(-1.44269504f * x));
}

__device__ __forceinline__ float tanhr(float x) {
    // clamp so exp2 can't produce inf -> NaN; tanh(16) == 1 to fp32
    float xx = fminf(fmaxf(x, -16.0f), 16.0f);
    float t = EXP2F(2.88539008f * xx);  // e^(2x)
    return (t - 1.0f) * RCPF(t + 1.0f);
}

// ---------------------------------------------------------------------------
// Kernel 1 (fused prep):
//  blocks [0,128):  proj[v][l*4+g] = dot(emb[v], W_ih[g*64+l]) + b_ih + b_hh (f16)
//  blocks [128,160): repack W_hh [256,64] f32 -> half2, lane-major:
//    flat n = l*128 + g*32 + j  <-  (W_hh[g*64+l][2j], W_hh[g*64+l][2j+1])
// ---------------------------------------------------------------------------
__global__ void k_prep(const float* __restrict__ emb, const float* __restrict__ Wih,
                       const float* __restrict__ bih, const float* __restrict__ bhh,
                       const float* __restrict__ Whh,
                       half1* __restrict__ proj, uint32_t* __restrict__ whh) {
    int tid = threadIdx.x;  // 0..255
    if (blockIdx.x < V_) {
        int v = blockIdx.x;
        int l = tid >> 2, g = tid & 3;
        int row = g * 64 + l;
        const float4* e4 = (const float4*)(emb + v * E_);
        const float4* w4 = (const float4*)(Wih + row * E_);
        float acc = bih[row] + bhh[row];
#pragma unroll
        for (int i = 0; i < E_ / 4; ++i) {
            float4 a = e4[i];
            float4 b = w4[i];
            acc += a.x * b.x + a.y * b.y + a.z * b.z + a.w * b.w;
        }
        proj[v * G4_ + tid] = (half1)acc;  // coalesced: addr = v*256 + tid
    } else {
        int n = (blockIdx.x - V_) * 256 + tid;  // 0..8191
        int j = n & 31;
        int g = (n >> 5) & 3;
        int l = n >> 7;
        int row = g * 64 + l;
        half2_t h2 = {(half1)Whh[row * H_ + 2 * j], (half1)Whh[row * H_ + 2 * j + 1]};
        whh[n] = __builtin_bit_cast(uint32_t, h2);
    }
}

// ---------------------------------------------------------------------------
// Kernel 2: the recurrence. One wave (64 threads) per batch element.
// Lane L owns hidden unit L: carries c[L] in a register, computes all 4 gates
// for unit L via v_dot2_f32_f16 against f16 W_hh held entirely in ARCH VGPRs.
// __launch_bounds__(64,1): 512-VGPR budget so the 128-reg w[] array is NOT
// demoted to AGPRs (R1: (64,2) caused v_accvgpr_read per dot -> 805 cyc/step).
// Actual usage ~170 VGPR still gives 2 waves/SIMD in hardware.
// h is exchanged through a 128B LDS buffer (wave-lockstep, no barrier needed).
// ---------------------------------------------------------------------------
__launch_bounds__(64, 1)
__global__ void k_lstm(const int* __restrict__ x, const uint32_t* __restrict__ whh,
                       const half1* __restrict__ proj, const float* __restrict__ Wfc,
                       const float* __restrict__ bfc, float* __restrict__ logits) {
    int b = blockIdx.x;
    int L = threadIdx.x;  // 0..63

    __shared__ __align__(16) uint32_t hbuf[32];  // 64 halves: h[0..63]
    __shared__ int xrow[T_];

    // stage this batch element's index row into LDS
#pragma unroll
    for (int i = 0; i < T_ / 64; ++i) xrow[i * 64 + L] = x[b * T_ + i * 64 + L];
    if (L < 32) hbuf[L] = 0u;  // h0 = 0
    __syncthreads();

    // load lane L's W_hh slice: 128 half2 = 128 VGPRs, fully unrolled constant idx
    half2_t w[4][32];
    {
        const uint4* wb4 = (const uint4*)(whh + L * 128);
#pragma unroll
        for (int i = 0; i < 32; ++i) {
            uint4 q = wb4[i];
            int n = i * 4;
            w[(n + 0) >> 5][(n + 0) & 31] = bchalf2(q.x);
            w[(n + 1) >> 5][(n + 1) & 31] = bchalf2(q.y);
            w[(n + 2) >> 5][(n + 2) & 31] = bchalf2(q.z);
            w[(n + 3) >> 5][(n + 3) & 31] = bchalf2(q.w);
        }
    }

    float c = 0.0f;
    float h = 0.0f;

    // software-pipelined input projection (one step ahead)
    int v0 = xrow[0];
    uint2 pu = *(const uint2*)(proj + v0 * G4_ + L * 4);

    const uint4* hb4 = (const uint4*)hbuf;
    half1* hb16 = (half1*)&hbuf[0];

    for (int t = 0; t < T_; ++t) {
        // prefetch next step's projection (wraps to row 0's entry on last iter; harmless)
        int vn = xrow[(t + 1) & (T_ - 1)];
        uint2 pn = *(const uint2*)(proj + vn * G4_ + L * 4);

        float ai = 0.f, af = 0.f, ag = 0.f, ao = 0.f;
#pragma unroll
        for (int q = 0; q < 8; ++q) {
            uint4 hh = hb4[q];  // broadcast ds_read_b128 (uniform address)
            half2_t hv0 = bchalf2(hh.x), hv1 = bchalf2(hh.y);
            half2_t hv2 = bchalf2(hh.z), hv3 = bchalf2(hh.w);
            ai = FDOT2(w[0][q * 4 + 0], hv0, ai);
            af = FDOT2(w[1][q * 4 + 0], hv0, af);
            ag = FDOT2(w[2][q * 4 + 0], hv0, ag);
            ao = FDOT2(w[3][q * 4 + 0], hv0, ao);
            ai = FDOT2(w[0][q * 4 + 1], hv1, ai);
            af = FDOT2(w[1][q * 4 + 1], hv1, af);
            ag = FDOT2(w[2][q * 4 + 1], hv1, ag);
            ao = FDOT2(w[3][q * 4 + 1], hv1, ao);
            ai = FDOT2(w[0][q * 4 + 2], hv2, ai);
            af = FDOT2(w[1][q * 4 + 2], hv2, af);
            ag = FDOT2(w[2][q * 4 + 2], hv2, ag);
            ao = FDOT2(w[3][q * 4 + 2], hv2, ao);
            ai = FDOT2(w[0][q * 4 + 3], hv3, ai);
            af = FDOT2(w[1][q * 4 + 3], hv3, af);
            ag = FDOT2(w[2][q * 4 + 3], hv3, ag);
            ao = FDOT2(w[3][q * 4 + 3], hv3, ao);
        }

        half2_t pa = bchalf2(pu.x), pb = bchalf2(pu.y);
        float gi = ai + (float)pa[0];
        float gf = af + (float)pa[1];
        float gg = ag + (float)pb[0];
        float go = ao + (float)pb[1];

        float i_ = sigm(gi);
        float f_ = sigm(gf);
        float g_ = tanhr(gg);
        float o_ = sigm(go);
        c = f_ * c + i_ * g_;
        h = o_ * tanhr(c);

        // publish h[L] for next step; single wave => lockstep, no barrier
        __builtin_amdgcn_wave_barrier();
        hb16[L] = (half1)h;
        __builtin_amdgcn_wave_barrier();

        pu = pn;
    }

    // logits[b] = sum_L h[L] * W_fc[L] + b_fc
    float contrib = h * Wfc[L];
#pragma unroll
    for (int off = 32; off > 0; off >>= 1) contrib += __shfl_down(contrib, off, 64);
    if (L == 0) logits[b] = contrib + bfc[0];
}

// ---------------------------------------------------------------------------
// Kernel 3: BCEWithLogits(pos_weight) mean over B. Single block, deterministic.
// ---------------------------------------------------------------------------
__global__ void k_loss(const float* __restrict__ logits, const float* __restrict__ targets,
                       float* __restrict__ loss_out) {
    __shared__ float red[256];
    int tid = threadIdx.x;
    float acc = 0.0f;
    for (int i = tid; i < B_; i += 256) {
        float z = logits[i];
        float tg = targets[i];
        // log sigmoid(z) = min(z,0) - log1p(exp(-|z|)); log sigmoid(-z) = that - z
        float e = EXP2F(-1.44269504f * fabsf(z));
        float lsp = fminf(z, 0.0f) - log1pf(e);
        float lsn = lsp - z;
        acc += -(POS_W * tg * lsp + (1.0f - tg) * lsn);
    }
    red[tid] = acc;
    __syncthreads();
#pragma unroll
    for (int s = 128; s > 0; s >>= 1) {
        if (tid < s) red[tid] += red[tid + s];
        __syncthreads();
    }
    if (tid == 0) loss_out[0] = red[0] * (1.0f / (float)B_);
}

// ---------------------------------------------------------------------------
extern "C" void kernel_launch(void* const* d_in, const int* in_sizes, int n_in,
                              void* d_out, int out_size, void* d_ws, size_t ws_size,
                              hipStream_t stream) {
    const int* x = (const int*)d_in[0];
    const float* targets = (const float*)d_in[1];
    const float* emb = (const float*)d_in[2];
    const float* Wih = (const float*)d_in[3];
    const float* Whh = (const float*)d_in[4];
    const float* bih = (const float*)d_in[5];
    const float* bhh = (const float*)d_in[6];
    const float* Wfc = (const float*)d_in[7];
    const float* bfc = (const float*)d_in[8];
    float* out = (float*)d_out;  // [0..2047] logits, [2048] loss

    half1* proj = (half1*)d_ws;                              // 128*256*2 = 64 KiB
    uint32_t* whh = (uint32_t*)((char*)d_ws + 64 * 1024);    // 8192*4   = 32 KiB

    k_prep<<<dim3(V_ + 32), dim3(256), 0, stream>>>(emb, Wih, bih, bhh, Whh, proj, whh);
    k_lstm<<<dim3(B_), dim3(64), 0, stream>>>(x, whh, proj, Wfc, bfc, out);
    k_loss<<<dim3(1), dim3(256), 0, stream>>>(out, targets, out + B_);
}